// Round 10
// baseline (123.369 us; speedup 1.0000x reference)
//
#include <hip/hip_runtime.h>

// AttentiveConv3d: B=2, C=128, T=16, H=W=28, heads=2, HS=64, K=27 (3x3x3, pad 1)
// Round 10: projection-first ("z-reorder") pipeline, all stages massive-TLP.
//   out[co,p] = b[co] + sum_k sum_h aw_h[k,p] * z_h[co, p+off_k]
//   where z_h[co,p] = sum_j W[co,2j+h] * x[2j+h,p]   (pointwise GEMM -> MFMA)
//   K1 xprep  : x -> bf16 transposed xbt[h][P][j]; W -> bf16 Wb[h][co][j]
//   K2 qfield : s[h][b][p] = sum_c q~[h,c] * x[b,c,p]
//   K3 aweight: aw[b][h][k][p] softmax, OOB weights folded to 0
//   K4 zgemm  : z[h][co][P] via mfma_f32_16x16x32_bf16 (LDS-free, barrier-free)
//   K5 combine: 9-row-window weighted combine of z (2 heads), aw in LDS.

#define TT 16
#define HH 28
#define WW 28
#define CC 128
#define SP (TT * HH * WW)   // 12544
#define NPOS (2 * SP)       // 25088
#define HS 64
#define KT 27

typedef __attribute__((ext_vector_type(8))) short bf16x8;
typedef __attribute__((ext_vector_type(4))) float f32x4;
typedef __attribute__((ext_vector_type(8))) unsigned short u16x8;

__device__ __forceinline__ unsigned short bf16_rtne(float f) {
    unsigned u = __float_as_uint(f);
    unsigned r = (u + 0x7FFFu + ((u >> 16) & 1u)) >> 16;
    return (unsigned short)r;
}

// ---- K1: x[b, 2j+h, sp] -> xbt[h][P][j] (bf16); W[co, 2j+h] -> Wb[h][co][j] ----
__global__ __launch_bounds__(256) void xprep_kernel(
    const float* __restrict__ x, const float* __restrict__ Wout,
    unsigned short* __restrict__ xbt, unsigned short* __restrict__ Wb)
{
    __shared__ float s_x[64][65];
    const int bx  = blockIdx.x;        // 784 = 2h * 392
    const int h   = bx & 1;
    const int pc  = bx >> 1;           // 0..391
    const int P0  = pc * 64;
    const int b   = P0 / SP;
    const int sp0 = P0 % SP;           // 64-aligned, SP % 64 == 0
    const int tid = threadIdx.x;

    #pragma unroll
    for (int it = 0; it < 4; ++it) {
        const int idx = it * 256 + tid;      // 1024 float4s: 64 j-rows x 16
        const int j   = idx >> 4;
        const int c16 = idx & 15;
        const float4 vv = *(const float4*)&x[(size_t)(b * CC + 2 * j + h) * SP + sp0 + c16 * 4];
        s_x[j][c16 * 4 + 0] = vv.x;
        s_x[j][c16 * 4 + 1] = vv.y;
        s_x[j][c16 * 4 + 2] = vv.z;
        s_x[j][c16 * 4 + 3] = vv.w;
    }
    if (pc == 0) {   // convert this head's W columns
        for (int i = tid; i < CC * HS; i += 256) {
            const int co = i >> 6, j = i & 63;
            Wb[(size_t)h * CC * HS + co * HS + j] = bf16_rtne(Wout[co * CC + 2 * j + h]);
        }
    }
    __syncthreads();
    #pragma unroll
    for (int it = 0; it < 2; ++it) {
        const int task = it * 256 + tid;     // 512: 64 P-rows x 8 j-parts
        const int pr = task >> 3;
        const int jp = task & 7;
        u16x8 pk;
        #pragma unroll
        for (int i = 0; i < 8; ++i) pk[i] = bf16_rtne(s_x[jp * 8 + i][pr]);
        *(u16x8*)&xbt[((size_t)h * NPOS + P0 + pr) * HS + jp * 8] = pk;
    }
}

// ---- K2: logit field ----
__global__ __launch_bounds__(256) void qfield_kernel(
    const float* __restrict__ x, const float* __restrict__ q,
    float* __restrict__ s)
{
    __shared__ float sp[16][32];
    const int tid = threadIdx.x;
    const int pl  = tid & 31;
    const int g   = tid >> 5;
    const int p   = blockIdx.x * 32 + pl;
    const int b   = p / SP;
    const int si  = p % SP;
    const float* xb = x + (size_t)b * CC * SP + si;

    float acc0 = 0.f, acc1 = 0.f;
    #pragma unroll
    for (int j = 0; j < 16; ++j) {
        const int c = g * 16 + j;
        const float val = xb[(size_t)c * SP];
        const float qv  = q[(c & 1) * HS + (c >> 1)] * (1.0f / 64.0f);
        if (c & 1) acc1 += qv * val; else acc0 += qv * val;
    }
    sp[g][pl]     = acc0;
    sp[8 + g][pl] = acc1;
    __syncthreads();
    if (tid < 64) {
        const int h = tid >> 5, pp = tid & 31;
        float a = 0.f;
        #pragma unroll
        for (int g2 = 0; g2 < 8; ++g2) a += sp[h * 8 + g2][pp];
        s[h * NPOS + blockIdx.x * 32 + pp] = a;
    }
}

// ---- K3: attention weights ----
__global__ __launch_bounds__(256) void aweight_kernel(
    const float* __restrict__ s, float* __restrict__ aw)
{
    const int idx = blockIdx.x * 256 + threadIdx.x;   // 4*SP
    const int p = idx % SP;
    const int h = (idx / SP) & 1;
    const int b = idx / (2 * SP);
    const int v = p % WW, u = (p / WW) % HH, t = p / (WW * HH);
    const float* sf = s + h * NPOS + b * SP;

    float l[KT], msk[KT];
    #pragma unroll
    for (int k = 0; k < KT; ++k) {
        const int dt = k / 9 - 1, du = (k / 3) % 3 - 1, dv = k % 3 - 1;
        const int tt = t + dt, uu = u + du, vv = v + dv;
        const bool ok = (unsigned)tt < TT && (unsigned)uu < HH && (unsigned)vv < WW;
        l[k]   = ok ? sf[(tt * HH + uu) * WW + vv] : 0.f;
        msk[k] = ok ? 1.f : 0.f;
    }
    float m = l[0];
    #pragma unroll
    for (int k = 1; k < KT; ++k) m = fmaxf(m, l[k]);
    float sum = 0.f;
    #pragma unroll
    for (int k = 0; k < KT; ++k) { l[k] = __expf(l[k] - m); sum += l[k]; }
    const float inv = 1.f / sum;
    float* awp = aw + (size_t)(b * 2 + h) * KT * SP + p;
    #pragma unroll
    for (int k = 0; k < KT; ++k)
        awp[(size_t)k * SP] = l[k] * inv * msk[k];
}

// ---- K4: z[h][co][P] = Wb[h] @ xbt[h]^T via MFMA (barrier-free, LDS-free) ----
// gemm_bt package: A row-frag [m][k], B^T row-frag [n][k], D col=lane&15,
// row=(lane>>4)*4+reg (guide §3, m89/m93 verified).
__global__ __launch_bounds__(256) void zgemm_kernel(
    const unsigned short* __restrict__ xbt, const unsigned short* __restrict__ Wb,
    float* __restrict__ z)
{
    const int bx = blockIdx.x;     // 1568 = 2h * 784
    const int h  = bx & 1;
    const int P0 = (bx >> 1) * 32;
    const int w    = threadIdx.x >> 6;   // wave 0..3
    const int lane = threadIdx.x & 63;
    const int lr = lane & 15;
    const int lk = lane >> 4;

    const unsigned short* Wh = Wb  + (size_t)h * CC * HS;
    const unsigned short* Xh = xbt + (size_t)h * NPOS * HS;

    #pragma unroll
    for (int ci = 0; ci < 2; ++ci) {
        const int cot = w * 2 + ci;          // 8 co-tiles over 4 waves
        #pragma unroll
        for (int pt = 0; pt < 2; ++pt) {
            f32x4 acc = {0.f, 0.f, 0.f, 0.f};
            #pragma unroll
            for (int ks = 0; ks < 2; ++ks) {
                const bf16x8 a  = *(const bf16x8*)&Wh[(cot * 16 + lr) * HS + ks * 32 + lk * 8];
                const bf16x8 bb = *(const bf16x8*)&Xh[(size_t)(P0 + pt * 16 + lr) * HS + ks * 32 + lk * 8];
                acc = __builtin_amdgcn_mfma_f32_16x16x32_bf16(a, bb, acc, 0, 0, 0);
            }
            #pragma unroll
            for (int r = 0; r < 4; ++r) {
                const int co = cot * 16 + lk * 4 + r;
                z[((size_t)h * CC + co) * NPOS + P0 + pt * 16 + lr] = acc[r];
            }
        }
    }
}

// ---- K5: out[co,p] = b[co] + sum_k,h aw_h[k,p] * z_h[co,p+off_k] ----
__global__ __launch_bounds__(256) void combine_kernel(
    const float* __restrict__ z, const float* __restrict__ aw,
    const float* __restrict__ bout, float* __restrict__ out)
{
    __shared__ float s_aw[2 * KT * 16];     // 3.4 KB
    const int bx   = blockIdx.x;            // 3136 = 2b * 2cog * 784
    const int spc  = bx % 784;
    const int rest = bx / 784;
    const int cogb = rest & 1;
    const int b    = rest >> 1;
    const int sp0  = spc * 16;
    const int tid  = threadIdx.x;

    for (int jj = tid; jj < 2 * KT * 16; jj += 256) {
        const int hk = jj >> 4, col = jj & 15;
        s_aw[jj] = aw[(size_t)(b * 2 * KT + hk) * SP + sp0 + col];
    }
    __syncthreads();

    const int co = cogb * 64 + (tid >> 2);
    const int s4 = tid & 3;
    const int sp = sp0 + s4 * 4;
    const int v0 = sp % WW;                 // 4-aligned, never crosses a row
    const int u  = (sp / WW) % HH;
    const int t  = sp / (WW * HH);
    const int vl = (v0 == 0)  ? 0  : v0 - 1;
    const int vr = (v0 == 24) ? 27 : v0 + 4;

    const float bb = bout[co];
    float4 acc = make_float4(bb, bb, bb, bb);

    const float* z0 = z + ((size_t)0 * CC + co) * NPOS + b * SP;
    const float* z1 = z + ((size_t)1 * CC + co) * NPOS + b * SP;

    #pragma unroll
    for (int dt = -1; dt <= 1; ++dt) {
        #pragma unroll
        for (int du = -1; du <= 1; ++du) {
            const int tt = t + dt, uu = u + du;
            const bool rok = ((unsigned)tt < TT) && ((unsigned)uu < HH);
            const int rbase = rok ? (tt * HH + uu) * WW : 0;   // aw=0 if row OOB
            const int kb = ((dt + 1) * 3 + (du + 1)) * 3;      // k = kb + (dv+1)
            #pragma unroll
            for (int h = 0; h < 2; ++h) {
                const float* zc = h ? z1 : z0;
                const float4 a  = *(const float4*)&zc[rbase + v0];
                const float  xl = zc[rbase + vl];
                const float  xr = zc[rbase + vr];
                const float* awb = &s_aw[(h * KT + kb) * 16 + s4 * 4];
                const float4 wm = *(const float4*)&awb[0];
                const float4 w0 = *(const float4*)&awb[16];
                const float4 wp = *(const float4*)&awb[32];
                // dv=-1: (xl,a.x,a.y,a.z); dv=0: a; dv=+1: (a.y,a.z,a.w,xr)
                acc.x += wm.x * xl;  acc.y += wm.y * a.x; acc.z += wm.z * a.y; acc.w += wm.w * a.z;
                acc.x += w0.x * a.x; acc.y += w0.y * a.y; acc.z += w0.z * a.z; acc.w += w0.w * a.w;
                acc.x += wp.x * a.y; acc.y += wp.y * a.z; acc.z += wp.z * a.w; acc.w += wp.w * xr;
            }
        }
    }
    *(float4*)&out[(size_t)(b * CC + co) * SP + sp] = acc;
}

extern "C" void kernel_launch(void* const* d_in, const int* in_sizes, int n_in,
                              void* d_out, int out_size, void* d_ws, size_t ws_size,
                              hipStream_t stream) {
    const float* x    = (const float*)d_in[0];
    const float* q    = (const float*)d_in[1];
    const float* Wout = (const float*)d_in[2];
    const float* bout = (const float*)d_in[3];
    float* out = (float*)d_out;

    float* s  = (float*)d_ws;                             // 25088 f32
    float* aw = s + NPOS;                                 // 4*27*SP f32
    unsigned short* Wb  = (unsigned short*)(aw + (size_t)4 * KT * SP);  // 16384 u16
    unsigned short* xbt = Wb + 2 * CC * HS;               // 2*NPOS*64 u16
    float* z = (float*)(xbt + (size_t)2 * NPOS * HS);     // 2*128*NPOS f32

    xprep_kernel  <<<dim3(784),        dim3(256), 0, stream>>>(x, Wout, xbt, Wb);
    qfield_kernel <<<dim3(NPOS / 32),  dim3(256), 0, stream>>>(x, q, s);
    aweight_kernel<<<dim3(4 * SP / 256), dim3(256), 0, stream>>>(s, aw);
    zgemm_kernel  <<<dim3(1568),       dim3(256), 0, stream>>>(xbt, Wb, z);
    combine_kernel<<<dim3(3136),       dim3(256), 0, stream>>>(z, aw, bout, out);
}

// Round 11
// 65.009 us; speedup vs baseline: 1.8977x; 1.8977x over previous
//
#include <hip/hip_runtime.h>

// AttentiveConv3d: B=2, C=128, T=16, H=W=28, heads=2, HS=64, K=27 (3x3x3, pad 1)
// Round 11: r7 structure, fusedmp at 512 threads/block (TP=32, grid 784).
// Thread supply doubles (12.25 -> 24.5 waves/CU); per-thread work halves;
// per-block traffic (x halo, W) unchanged vs r7.
//   K1 qfield : s[h][b][p] = sum_c q~[h,c] * x[b,c,p]              (200 KB)
//   K2 aweight: aw[b][h][k][p] softmax, OOB weights folded to 0    (5.4 MB)
//   K3 fusedmp: per 32-p tile: aw -> LDS; phase B (9-row-window merge -> LDS,
//               2 float4-tasks/thread); phase C (2co x 4p float4 projection).

#define TT 16
#define HH 28
#define WW 28
#define CC 128
#define SP (TT * HH * WW)   // 12544 = 392*32
#define NPOS (2 * SP)       // 25088
#define HS 64
#define KT 27
#define TP 32               // positions per fused tile

__global__ __launch_bounds__(256) void qfield_kernel(
    const float* __restrict__ x, const float* __restrict__ q,
    float* __restrict__ s)
{
    __shared__ float sp[16][32];     // [h*8+g][pos_local]
    const int tid = threadIdx.x;
    const int pl  = tid & 31;
    const int g   = tid >> 5;        // channel group 0..7
    const int p   = blockIdx.x * 32 + pl;
    const int b   = p / SP;
    const int si  = p % SP;
    const float* xb = x + (size_t)b * CC * SP + si;

    float acc0 = 0.f, acc1 = 0.f;    // head 0 / head 1 partials
    #pragma unroll
    for (int j = 0; j < 16; ++j) {
        const int c = g * 16 + j;              // channel
        const float val = xb[(size_t)c * SP];
        const float qv  = q[(c & 1) * HS + (c >> 1)] * (1.0f / 64.0f);
        if (c & 1) acc1 += qv * val; else acc0 += qv * val;
    }
    sp[g][pl]     = acc0;
    sp[8 + g][pl] = acc1;
    __syncthreads();
    if (tid < 64) {
        const int h = tid >> 5, pp = tid & 31;
        float a = 0.f;
        #pragma unroll
        for (int g2 = 0; g2 < 8; ++g2) a += sp[h * 8 + g2][pp];
        s[h * NPOS + blockIdx.x * 32 + pp] = a;
    }
}

// thread = (b, h, p);  aw[((b*2+h)*KT + k)*SP + p]
__global__ __launch_bounds__(256) void aweight_kernel(
    const float* __restrict__ s, float* __restrict__ aw)
{
    const int idx = blockIdx.x * 256 + threadIdx.x;   // 4*SP = 50176 exactly
    const int p = idx % SP;
    const int h = (idx / SP) & 1;
    const int b = idx / (2 * SP);
    const int v = p % WW, u = (p / WW) % HH, t = p / (WW * HH);
    const float* sf = s + h * NPOS + b * SP;

    float l[KT], msk[KT];
    #pragma unroll
    for (int k = 0; k < KT; ++k) {
        const int dt = k / 9 - 1, du = (k / 3) % 3 - 1, dv = k % 3 - 1;
        const int tt = t + dt, uu = u + du, vv = v + dv;
        const bool ok = (unsigned)tt < TT && (unsigned)uu < HH && (unsigned)vv < WW;
        l[k]   = ok ? sf[(tt * HH + uu) * WW + vv] : 0.f;  // OOB logit = 0 (pad)
        msk[k] = ok ? 1.f : 0.f;
    }
    float m = l[0];
    #pragma unroll
    for (int k = 1; k < KT; ++k) m = fmaxf(m, l[k]);
    float sum = 0.f;
    #pragma unroll
    for (int k = 0; k < KT; ++k) { l[k] = __expf(l[k] - m); sum += l[k]; }
    const float inv = 1.f / sum;
    float* awp = aw + (size_t)(b * 2 + h) * KT * SP + p;
    #pragma unroll
    for (int k = 0; k < KT; ++k)
        awp[(size_t)k * SP] = l[k] * inv * msk[k];   // OOB weight folded to 0
}

// block = 32-p tile of one batch (grid 784), 512 threads.
// stage aw[2][27][32] -> LDS; phase B: 1024 float4-tasks, 2/thread -> LDS;
// phase C: cog 0..63 x vg 0..7; 2 co x 4 p (float4) per thread.
__global__ __launch_bounds__(512) void fusedmp_kernel(
    const float* __restrict__ x, const float* __restrict__ aw,
    const float* __restrict__ Wout, const float* __restrict__ bout,
    float* __restrict__ out)
{
    __shared__ float s_m[CC][TP];            // 16 KB
    __shared__ float s_aw[2][KT][TP];        // 6.75 KB

    const int pb  = blockIdx.x;              // 2 * 392
    const int b   = pb / (SP / TP);
    const int p0  = (pb % (SP / TP)) * TP;
    const int tid = threadIdx.x;

    // ---- stage aw slice: 2*27*32 = 1728 floats, coalesced ----
    for (int j = tid; j < 2 * KT * TP; j += 512) {
        const int col = j & (TP - 1);
        const int hk  = j / TP;              // h*KT + k
        s_aw[0][0][j] = aw[((size_t)(b * 2) * KT + hk) * SP + p0 + col];
    }
    __syncthreads();

    // ---- phase B: 1024 float4-tasks (128 c x 8 p4-groups), 2 per thread ----
    #pragma unroll
    for (int it = 0; it < 2; ++it) {
        const int task = it * 512 + tid;     // 0..1023
        const int c    = task >> 3;
        const int p4g  = task & 7;
        const int p    = p0 + p4g * 4;
        const int v0   = p % WW;             // 4-aligned, never crosses a row
        const int u    = (p / WW) % HH;
        const int t    = p / (WW * HH);
        const int h    = c & 1;
        const float* xc = x + (size_t)(b * CC + c) * SP;
        const int vl = (v0 == 0)  ? 0  : v0 - 1;   // clamped edges (aw=0 there)
        const int vr = (v0 == 24) ? 27 : v0 + 4;

        float4 acc = make_float4(0.f, 0.f, 0.f, 0.f);
        #pragma unroll
        for (int dt = -1; dt <= 1; ++dt) {
            #pragma unroll
            for (int du = -1; du <= 1; ++du) {
                const int tt = t + dt, uu = u + du;
                const bool rok = ((unsigned)tt < TT) && ((unsigned)uu < HH);
                const int rbase = rok ? (tt * HH + uu) * WW : 0;  // aw=0 if row OOB
                const float4 a  = *(const float4*)&xc[rbase + v0];
                const float  xl = xc[rbase + vl];
                const float  xr = xc[rbase + vr];
                const int kb = ((dt + 1) * 3 + (du + 1)) * 3;     // k = kb + (dv+1)
                const float4 wm = *(const float4*)&s_aw[h][kb + 0][p4g * 4];
                const float4 w0 = *(const float4*)&s_aw[h][kb + 1][p4g * 4];
                const float4 wp = *(const float4*)&s_aw[h][kb + 2][p4g * 4];
                // dv=-1: (xl, a.x, a.y, a.z); dv=0: a; dv=+1: (a.y, a.z, a.w, xr)
                acc.x += wm.x * xl;  acc.y += wm.y * a.x; acc.z += wm.z * a.y; acc.w += wm.w * a.z;
                acc.x += w0.x * a.x; acc.y += w0.y * a.y; acc.z += w0.z * a.z; acc.w += w0.w * a.w;
                acc.x += wp.x * a.y; acc.y += wp.y * a.z; acc.z += wp.z * a.w; acc.w += wp.w * xr;
            }
        }
        *(float4*)&s_m[c][p4g * 4] = acc;
    }
    __syncthreads();

    // ---- phase C: y[co][p] = b[co] + sum_ci W[co][ci]*merged[ci][p] ----
    const int cog = tid >> 3;              // 0..63, co = cog*2 + {0,1}
    const int vg  = tid & 7;               // p = p0 + vg*4 + vec-lane
    const float4* w0 = (const float4*)(Wout + (size_t)(cog * 2 + 0) * CC);
    const float4* w1 = (const float4*)(Wout + (size_t)(cog * 2 + 1) * CC);

    const float b0 = bout[cog * 2 + 0];
    const float b1 = bout[cog * 2 + 1];
    float4 acc0 = make_float4(b0, b0, b0, b0);
    float4 acc1 = make_float4(b1, b1, b1, b1);

    #pragma unroll 8
    for (int q4 = 0; q4 < CC / 4; ++q4) {
        const float4 wa = w0[q4];
        const float4 wb = w1[q4];
        const float4 m0 = *(const float4*)&s_m[q4 * 4 + 0][vg * 4];
        const float4 m1 = *(const float4*)&s_m[q4 * 4 + 1][vg * 4];
        const float4 m2 = *(const float4*)&s_m[q4 * 4 + 2][vg * 4];
        const float4 m3 = *(const float4*)&s_m[q4 * 4 + 3][vg * 4];
        acc0.x += wa.x * m0.x + wa.y * m1.x + wa.z * m2.x + wa.w * m3.x;
        acc0.y += wa.x * m0.y + wa.y * m1.y + wa.z * m2.y + wa.w * m3.y;
        acc0.z += wa.x * m0.z + wa.y * m1.z + wa.z * m2.z + wa.w * m3.z;
        acc0.w += wa.x * m0.w + wa.y * m1.w + wa.z * m2.w + wa.w * m3.w;
        acc1.x += wb.x * m0.x + wb.y * m1.x + wb.z * m2.x + wb.w * m3.x;
        acc1.y += wb.x * m0.y + wb.y * m1.y + wb.z * m2.y + wb.w * m3.y;
        acc1.z += wb.x * m0.z + wb.y * m1.z + wb.z * m2.z + wb.w * m3.z;
        acc1.w += wb.x * m0.w + wb.y * m1.w + wb.z * m2.w + wb.w * m3.w;
    }

    const size_t ob = (size_t)b * CC * SP + p0 + vg * 4;
    *(float4*)&out[ob + (size_t)(cog * 2 + 0) * SP] = acc0;
    *(float4*)&out[ob + (size_t)(cog * 2 + 1) * SP] = acc1;
}

extern "C" void kernel_launch(void* const* d_in, const int* in_sizes, int n_in,
                              void* d_out, int out_size, void* d_ws, size_t ws_size,
                              hipStream_t stream) {
    const float* x    = (const float*)d_in[0];
    const float* q    = (const float*)d_in[1];
    const float* Wout = (const float*)d_in[2];
    const float* bout = (const float*)d_in[3];
    float* out = (float*)d_out;

    float* s  = (float*)d_ws;                        // 50176 floats
    float* aw = s + NPOS;                            // 4*27*SP floats

    qfield_kernel <<<dim3(NPOS / 32),     dim3(256), 0, stream>>>(x, q, s);
    aweight_kernel<<<dim3(4 * SP / 256),  dim3(256), 0, stream>>>(s, aw);
    fusedmp_kernel<<<dim3(2 * (SP / TP)), dim3(512), 0, stream>>>(x, aw, Wout, bout, out);
}

// Round 12
// 61.789 us; speedup vs baseline: 1.9966x; 1.0521x over previous
//
#include <hip/hip_runtime.h>

// AttentiveConv3d: B=2, C=128, T=16, H=W=28, heads=2, HS=64, K=27 (3x3x3, pad 1)
// Round 12: r7 exactly (best, 61.2us) + bijective XCD-aware block swizzle on
// fusedmp (784 = 8 XCD x 98 contiguous p-tiles -> per-XCD x slab ~1.6MB fits
// its private 4MB L2; halo rows become L2 hits instead of HBM re-fetches).
//   K1 qfield : s[h][b][p] = sum_c q~[h,c] * x[b,c,p]              (200 KB)
//   K2 aweight: aw[b][h][k][p] softmax, OOB weights folded to 0    (5.4 MB)
//   K3 fusedmp: per 32-p tile: phase B (9-row-window merge -> LDS),
//               phase C (4co x 4p float4 projection, W via L1/L2).

#define TT 16
#define HH 28
#define WW 28
#define CC 128
#define SP (TT * HH * WW)   // 12544 = 392*32
#define NPOS (2 * SP)       // 25088
#define HS 64
#define KT 27

__global__ __launch_bounds__(256) void qfield_kernel(
    const float* __restrict__ x, const float* __restrict__ q,
    float* __restrict__ s)
{
    __shared__ float sp[16][32];     // [h*8+g][pos_local]
    const int tid = threadIdx.x;
    const int pl  = tid & 31;
    const int g   = tid >> 5;        // channel group 0..7
    const int p   = blockIdx.x * 32 + pl;
    const int b   = p / SP;
    const int si  = p % SP;
    const float* xb = x + (size_t)b * CC * SP + si;

    float acc0 = 0.f, acc1 = 0.f;    // head 0 / head 1 partials
    #pragma unroll
    for (int j = 0; j < 16; ++j) {
        const int c = g * 16 + j;              // channel
        const float val = xb[(size_t)c * SP];
        const float qv  = q[(c & 1) * HS + (c >> 1)] * (1.0f / 64.0f);
        if (c & 1) acc1 += qv * val; else acc0 += qv * val;
    }
    sp[g][pl]     = acc0;
    sp[8 + g][pl] = acc1;
    __syncthreads();
    if (tid < 64) {
        const int h = tid >> 5, pp = tid & 31;
        float a = 0.f;
        #pragma unroll
        for (int g2 = 0; g2 < 8; ++g2) a += sp[h * 8 + g2][pp];
        s[h * NPOS + blockIdx.x * 32 + pp] = a;
    }
}

// thread = (b, h, p);  aw[((b*2+h)*KT + k)*SP + p]
__global__ __launch_bounds__(256) void aweight_kernel(
    const float* __restrict__ s, float* __restrict__ aw)
{
    const int idx = blockIdx.x * 256 + threadIdx.x;   // 4*SP = 50176 exactly
    const int p = idx % SP;
    const int h = (idx / SP) & 1;
    const int b = idx / (2 * SP);
    const int v = p % WW, u = (p / WW) % HH, t = p / (WW * HH);
    const float* sf = s + h * NPOS + b * SP;

    float l[KT], msk[KT];
    #pragma unroll
    for (int k = 0; k < KT; ++k) {
        const int dt = k / 9 - 1, du = (k / 3) % 3 - 1, dv = k % 3 - 1;
        const int tt = t + dt, uu = u + du, vv = v + dv;
        const bool ok = (unsigned)tt < TT && (unsigned)uu < HH && (unsigned)vv < WW;
        l[k]   = ok ? sf[(tt * HH + uu) * WW + vv] : 0.f;  // OOB logit = 0 (pad)
        msk[k] = ok ? 1.f : 0.f;
    }
    float m = l[0];
    #pragma unroll
    for (int k = 1; k < KT; ++k) m = fmaxf(m, l[k]);
    float sum = 0.f;
    #pragma unroll
    for (int k = 0; k < KT; ++k) { l[k] = __expf(l[k] - m); sum += l[k]; }
    const float inv = 1.f / sum;
    float* awp = aw + (size_t)(b * 2 + h) * KT * SP + p;
    #pragma unroll
    for (int k = 0; k < KT; ++k)
        awp[(size_t)k * SP] = l[k] * inv * msk[k];   // OOB weight folded to 0
}

// block = 32-p tile of one batch (grid 784, XCD-swizzled).
__global__ __launch_bounds__(256) void fusedmp_kernel(
    const float* __restrict__ x, const float* __restrict__ aw,
    const float* __restrict__ Wout, const float* __restrict__ bout,
    float* __restrict__ out)
{
    __shared__ float s_m[CC][32];          // 16 KB

    // ---- bijective XCD swizzle: 784 = 8 * 98; HW maps bid%8 -> XCD, so
    // blocks with bid%8 == j get contiguous tile range [j*98, (j+1)*98).
    const int pb  = (blockIdx.x & 7) * 98 + (blockIdx.x >> 3);
    const int b   = pb / (SP / 32);
    const int p0  = (pb % (SP / 32)) * 32;
    const int tid = threadIdx.x;

    // ---- phase B: 1024 float4-tasks (c x 8 p4-groups), 4 per thread ----
    #pragma unroll
    for (int it = 0; it < 4; ++it) {
        const int task = it * 256 + tid;   // 0..1023
        const int c    = task >> 3;
        const int p4g  = task & 7;
        const int p    = p0 + p4g * 4;
        const int v0   = p % WW;           // 4-aligned, never crosses a row
        const int u    = (p / WW) % HH;
        const int t    = p / (WW * HH);
        const int h    = c & 1;
        const float* xc  = x + (size_t)(b * CC + c) * SP;
        const float* awp = aw + (size_t)(b * 2 + h) * KT * SP + p;
        const int vl = (v0 == 0)  ? 0  : v0 - 1;   // clamped edges (aw=0 there)
        const int vr = (v0 == 24) ? 27 : v0 + 4;

        float4 acc = make_float4(0.f, 0.f, 0.f, 0.f);
        #pragma unroll
        for (int dt = -1; dt <= 1; ++dt) {
            #pragma unroll
            for (int du = -1; du <= 1; ++du) {
                const int tt = t + dt, uu = u + du;
                const bool rok = ((unsigned)tt < TT) && ((unsigned)uu < HH);
                const int rbase = rok ? (tt * HH + uu) * WW : 0;  // aw=0 if row OOB
                const float4 a  = *(const float4*)&xc[rbase + v0];
                const float  xl = xc[rbase + vl];
                const float  xr = xc[rbase + vr];
                const int kb = ((dt + 1) * 3 + (du + 1)) * 3;     // k = kb + (dv+1)
                const float4 wm = *(const float4*)&awp[(size_t)(kb + 0) * SP];
                const float4 w0 = *(const float4*)&awp[(size_t)(kb + 1) * SP];
                const float4 wp = *(const float4*)&awp[(size_t)(kb + 2) * SP];
                // dv=-1: (xl, a.x, a.y, a.z); dv=0: a; dv=+1: (a.y, a.z, a.w, xr)
                acc.x += wm.x * xl;  acc.y += wm.y * a.x; acc.z += wm.z * a.y; acc.w += wm.w * a.z;
                acc.x += w0.x * a.x; acc.y += w0.y * a.y; acc.z += w0.z * a.z; acc.w += w0.w * a.w;
                acc.x += wp.x * a.y; acc.y += wp.y * a.z; acc.z += wp.z * a.w; acc.w += wp.w * xr;
            }
        }
        *(float4*)&s_m[c][p4g * 4] = acc;
    }
    __syncthreads();

    // ---- phase C: y[co][p] = b[co] + sum_ci W[co][ci]*merged[ci][p] ----
    const int cog = tid >> 3;              // co = cog*4 + c
    const int vg  = tid & 7;               // p = p0 + vg*4 + (vec lane)
    const float4* w0 = (const float4*)(Wout + (size_t)(cog * 4 + 0) * CC);
    const float4* w1 = (const float4*)(Wout + (size_t)(cog * 4 + 1) * CC);
    const float4* w2 = (const float4*)(Wout + (size_t)(cog * 4 + 2) * CC);
    const float4* w3 = (const float4*)(Wout + (size_t)(cog * 4 + 3) * CC);

    float4 acc[4];
    #pragma unroll
    for (int c = 0; c < 4; ++c) {
        const float bb = bout[cog * 4 + c];
        acc[c] = make_float4(bb, bb, bb, bb);
    }

    #pragma unroll 8
    for (int q4 = 0; q4 < CC / 4; ++q4) {
        float4 w4[4] = { w0[q4], w1[q4], w2[q4], w3[q4] };
        float4 m0 = *(const float4*)&s_m[q4 * 4 + 0][vg * 4];
        float4 m1 = *(const float4*)&s_m[q4 * 4 + 1][vg * 4];
        float4 m2 = *(const float4*)&s_m[q4 * 4 + 2][vg * 4];
        float4 m3 = *(const float4*)&s_m[q4 * 4 + 3][vg * 4];
        #pragma unroll
        for (int c = 0; c < 4; ++c) {
            acc[c].x += w4[c].x * m0.x + w4[c].y * m1.x + w4[c].z * m2.x + w4[c].w * m3.x;
            acc[c].y += w4[c].x * m0.y + w4[c].y * m1.y + w4[c].z * m2.y + w4[c].w * m3.y;
            acc[c].z += w4[c].x * m0.z + w4[c].y * m1.z + w4[c].z * m2.z + w4[c].w * m3.z;
            acc[c].w += w4[c].x * m0.w + w4[c].y * m1.w + w4[c].z * m2.w + w4[c].w * m3.w;
        }
    }

    #pragma unroll
    for (int c = 0; c < 4; ++c) {
        const int co = cog * 4 + c;
        *(float4*)&out[(size_t)(b * CC + co) * SP + p0 + vg * 4] = acc[c];
    }
}

extern "C" void kernel_launch(void* const* d_in, const int* in_sizes, int n_in,
                              void* d_out, int out_size, void* d_ws, size_t ws_size,
                              hipStream_t stream) {
    const float* x    = (const float*)d_in[0];
    const float* q    = (const float*)d_in[1];
    const float* Wout = (const float*)d_in[2];
    const float* bout = (const float*)d_in[3];
    float* out = (float*)d_out;

    float* s  = (float*)d_ws;                        // 50176 floats
    float* aw = s + NPOS;                            // 4*27*SP floats

    qfield_kernel <<<dim3(NPOS / 32),    dim3(256), 0, stream>>>(x, q, s);
    aweight_kernel<<<dim3(4 * SP / 256), dim3(256), 0, stream>>>(s, aw);
    fusedmp_kernel<<<dim3(2 * (SP / 32)),dim3(256), 0, stream>>>(x, aw, Wout, bout, out);
}